// Round 14
// baseline (1145.242 us; speedup 1.0000x reference)
//
#include <hip/hip_runtime.h>
#include <hip/hip_fp16.h>
#include <cstdint>

#define NT 256
#define N_ATOMS_C 600000
#define BATCH_C 24000

constexpr int K_COUNTS[11] = {10000,130000,170000,160000,100000,15000,5000,2500,2500,2500,2500};
constexpr int K_STARTS[11] = {0,10000,140000,310000,470000,570000,585000,590000,592500,595000,597500};
// heavy-degree-first dispatch order
constexpr int DORD[11] = {10,9,8,7,6,5,4,3,2,1,0};

struct AdjPtrs { const int* p[10]; };

__device__ __forceinline__ float selu_f(float x) {
    const float scale = 1.0507009873554805f;
    const float alpha = 1.6732632423543772f;
    return scale * (x > 0.f ? x : alpha * expm1f(x));
}

__device__ __forceinline__ float2 up2(unsigned u) {
    const __half2 h = __builtin_bit_cast(__half2, u);
    return __half22float2(h);
}
__device__ __forceinline__ unsigned pack2(float a, float b) {
    const __half2 h = __float22half2_rn(make_float2(a, b));
    return __builtin_bit_cast(unsigned, h);
}

template<int NLD4>
__device__ __forceinline__ void load_row(const uint2* __restrict__ p, float* r) {
#pragma unroll
    for (int v = 0; v < NLD4; ++v) {
        const uint2 t = p[v];
        const float2 a = up2(t.x), b = up2(t.y);
        r[4*v] = a.x; r[4*v+1] = a.y; r[4*v+2] = b.x; r[4*v+3] = b.y;
    }
}
template<int NLD4>
__device__ __forceinline__ void add_row(const uint2* __restrict__ p, float* r) {
#pragma unroll
    for (int v = 0; v < NLD4; ++v) {
        const uint2 t = p[v];
        const float2 a = up2(t.x), b = up2(t.y);
        r[4*v] += a.x; r[4*v+1] += a.y; r[4*v+2] += b.x; r[4*v+3] += b.y;
    }
}
template<int NF, int FO>
__device__ __forceinline__ void fma_strip(const float* r, const float* __restrict__ w,
                                          float* acc) {
#pragma unroll
    for (int f = 0; f < NF; ++f)
#pragma unroll
        for (int o = 0; o < FO; ++o)
            acc[o] = fmaf(r[f], w[f * FO + o], acc[o]);
}

// block -> (degree, segment start, count, tile index within segment)
__device__ __forceinline__ void blk2deg(int blk, int& deg, int& s, int& cnt, int& tile) {
    deg = 0; s = 0; cnt = 0; tile = 0;
#pragma unroll
    for (int di = 0; di < 11; ++di) {
        const int d = DORD[di];
        const int nb = (K_COUNTS[d] + NT - 1) / NT;
        if (blk < nb) { deg = d; s = K_STARTS[d]; cnt = K_COUNTS[d]; tile = blk; return; }
        blk -= nb;
    }
}

// ---------------------------------------------------------------------------
// prep: per atom, z_d = x0 @ W[2(d-1)] (d=1..4) into 4 planes (N,16) fp16, and
// s = x0 @ Wb(own deg) + biases (fp16, 32B). Row staged in LDS once (fp16,
// stride 78 shorts -> conflict-free), held in 38 u32 VGPRs; 5 projections
// sequential (15 live accs each — no spill, r12-proven). Inner loop: scalar
// v_fma with f32 weights direct from W via wave-uniform s_load (src0=SGPR):
// per feature pair = 2 cvt + 30 fma -> ~6.2K VALU/thread, HALF of r12's 12K
// (r12's fdot2 fallback unpacked every weight pair: 2 cvt + 2 fma per pair).
// r13's pk_fma attempt scalarized AND blew VGPR to 104 -> 640us; reverted.
// ---------------------------------------------------------------------------
__global__ __launch_bounds__(256) void prep_kernel(
    const float* __restrict__ x0,    // (N, 75) f32
    const float* __restrict__ W,     // (21, 75, 15) f32
    const float* __restrict__ bias,  // (21, 15)
    const int* __restrict__ mem,
    int* __restrict__ cnt,
    unsigned short* __restrict__ z,  // 4 planes of (N, 16) fp16
    unsigned short* __restrict__ srow) // (N, 16) fp16
{
    __shared__ unsigned short sx[NT * 78];   // 39.9 KB; 39-dword rows (odd)

    int deg, s, c, tile;
    blk2deg(blockIdx.x, deg, s, c, tile);
    const int a0 = tile * NT;
    const int na = min(NT, c - a0);
    const int tid = threadIdx.x;

    // cooperative coalesced stage: na*75 f32 -> fp16 LDS; zero the pad short
    const float* src = x0 + (size_t)(s + a0) * 75;
    for (int i = tid; i < na * 75; i += NT) {
        const int j = i / 75, f = i - j * 75;
        sx[j * 78 + f] = __builtin_bit_cast(unsigned short, __float2half_rn(src[i]));
    }
    for (int j = tid; j < na; j += NT) sx[j * 78 + 75] = 0;
    __syncthreads();

    const int a = a0 + tid;
    if (a >= c) return;                      // no barriers after this point
    const int atom = s + a;

    // pull the whole row into registers (38 u32 = 76 feats incl. zero pad)
    unsigned xr[38];
    {
        const unsigned* row32 = reinterpret_cast<const unsigned*>(sx + tid * 78);
#pragma unroll
        for (int u = 0; u < 38; ++u) xr[u] = row32[u];
    }

    const int wi_b = deg ? (2 * deg - 1) : 20;

#pragma unroll 1
    for (int p = 0; p < 5; ++p) {
        const int wi = (p < 4) ? 2 * p : wi_b;
        const float* Wp = W + wi * 1125;

        float acc[15];
        if (p < 4) {
#pragma unroll
            for (int o = 0; o < 15; ++o) acc[o] = 0.f;
        } else {
#pragma unroll
            for (int o = 0; o < 15; ++o)
                acc[o] = bias[wi_b * 15 + o] + (deg ? bias[2 * (deg - 1) * 15 + o] : 0.f);
        }

#pragma unroll
        for (int u = 0; u < 38; ++u) {
            const float2 xv = up2(xr[u]);
            const float* w0 = Wp + (2 * u) * 15;
#pragma unroll
            for (int o = 0; o < 15; ++o) acc[o] = fmaf(xv.x, w0[o], acc[o]);
            if (2 * u + 1 < 75) {               // static: drops only pad feat 75
#pragma unroll
                for (int o = 0; o < 15; ++o) acc[o] = fmaf(xv.y, w0[15 + o], acc[o]);
            }
        }

        unsigned short* outp = (p < 4)
            ? (z + (size_t)p * (N_ATOMS_C * 16) + (size_t)atom * 16)
            : (srow + (size_t)atom * 16);
        uint4* o4 = reinterpret_cast<uint4*>(outp);
        o4[0] = make_uint4(pack2(acc[0], acc[1]),  pack2(acc[2], acc[3]),
                           pack2(acc[4], acc[5]),  pack2(acc[6], acc[7]));
        o4[1] = make_uint4(pack2(acc[8], acc[9]),  pack2(acc[10], acc[11]),
                           pack2(acc[12], acc[13]), pack2(acc[14], 0.f));
    }

    atomicAdd(&cnt[mem[atom]], 1);
}

// ---------------------------------------------------------------------------
// conv1: deg<=4 -> s + sum of gathered 32-B rows (2 x uint4) from z plane.
//        deg>=5 -> s + full x0-row gathers vs Wa (rare: 190K rows).
// ---------------------------------------------------------------------------
__global__ __launch_bounds__(256) void conv1_kernel(
    const float* __restrict__ x0,
    const unsigned short* __restrict__ z,     // 4 planes of (N,16)
    const unsigned short* __restrict__ srow,
    const float* __restrict__ W,
    AdjPtrs adjp,
    unsigned short* __restrict__ y1)  // (N, 16) fp16
{
    int deg, s, c, tile;
    blk2deg(blockIdx.x, deg, s, c, tile);
    const int a = tile * NT + threadIdx.x;
    if (a >= c) return;
    const int atom = s + a;

    float acc[15];
    {
        const uint2* sp = reinterpret_cast<const uint2*>(srow + (size_t)atom * 16);
        float r[16];
        load_row<4>(sp, r);
#pragma unroll
        for (int o = 0; o < 15; ++o) acc[o] = r[o];
    }

    if (deg >= 1 && deg <= 4) {
        const unsigned short* zd = z + (size_t)(deg - 1) * (N_ATOMS_C * 16);
        const int* ad = adjp.p[deg - 1] + (size_t)a * deg;
        int nb[4];
#pragma unroll
        for (int k = 0; k < 4; ++k) nb[k] = ad[k < deg ? k : 0];
        uint4 t[4][2];
#pragma unroll
        for (int k = 0; k < 4; ++k) {
            const uint4* p = reinterpret_cast<const uint4*>(zd + (size_t)nb[k] * 16);
            t[k][0] = p[0]; t[k][1] = p[1];
        }
#pragma unroll
        for (int k = 0; k < 4; ++k) {
            if (k < deg) {
                const unsigned w[8] = {t[k][0].x, t[k][0].y, t[k][0].z, t[k][0].w,
                                       t[k][1].x, t[k][1].y, t[k][1].z, t[k][1].w};
#pragma unroll
                for (int v = 0; v < 8; ++v) {
                    const float2 lo = up2(w[v]);
                    if (2 * v < 15)     acc[2 * v]     += lo.x;
                    if (2 * v + 1 < 15) acc[2 * v + 1] += lo.y;
                }
            }
        }
    } else if (deg >= 5) {
        const float* Wa = W + 2 * (deg - 1) * 1125;
        const int* ad = adjp.p[deg - 1] + (size_t)a * deg;
#pragma unroll 1
        for (int st = 0; st < 3; ++st) {
            float r[25];
#pragma unroll
            for (int j = 0; j < 25; ++j) r[j] = 0.f;
            for (int k = 0; k < deg; ++k) {
                const float* xr = x0 + (size_t)ad[k] * 75 + st * 25;
#pragma unroll
                for (int j = 0; j < 25; ++j) r[j] += xr[j];
            }
            fma_strip<25, 15>(r, Wa + st * 25 * 15, acc);
        }
    }

    uint2* yp = reinterpret_cast<uint2*>(y1 + (size_t)atom * 16);
    float o_[16];
#pragma unroll
    for (int o = 0; o < 16; ++o) o_[o] = (o < 15) ? selu_f(acc[o]) : 0.f;
    yp[0] = make_uint2(pack2(o_[0],o_[1]),  pack2(o_[2],o_[3]));
    yp[1] = make_uint2(pack2(o_[4],o_[5]),  pack2(o_[6],o_[7]));
    yp[2] = make_uint2(pack2(o_[8],o_[9]),  pack2(o_[10],o_[11]));
    yp[3] = make_uint2(pack2(o_[12],o_[13]),pack2(o_[14],o_[15]));
}

// ---------------------------------------------------------------------------
// Generic conv (layers 2-4): thread = atom, fp16 in/out, f32 accum.
// ---------------------------------------------------------------------------
template<int FIN, int FINP, int FO, int FOP, int FS>
__global__ __launch_bounds__(256) void conv_kernel(
    const unsigned short* __restrict__ x,  // (N, FINP) fp16
    const float* __restrict__ W,           // (21, FIN, FO)
    const float* __restrict__ bias,        // (21, FO)
    AdjPtrs adjp,
    unsigned short* __restrict__ y)        // (N, FOP) fp16
{
    static_assert(FS % 4 == 0 && FINP % 4 == 0 && FOP % 4 == 0, "");
    constexpr int NSF = FIN / FS;
    constexpr int TF  = FIN - NSF * FS;
    constexpr int TLD4 = (TF + 3) / 4;
    static_assert(NSF * FS + TLD4 * 4 <= FINP, "tail reads past row");

    int deg, s, c, tile;
    blk2deg(blockIdx.x, deg, s, c, tile);
    const int a = tile * NT + threadIdx.x;
    if (a >= c) return;
    const int atom = s + a;

    const int wi_a = (deg == 0) ? 20 : 2 * (deg - 1);
    const int wi_b = (deg == 0) ? 20 : 2 * deg - 1;
    const float* Wa = W + wi_a * FIN * FO;
    const float* Wb = W + wi_b * FIN * FO;

    float acc[FO];
#pragma unroll
    for (int o = 0; o < FO; ++o)
        acc[o] = bias[wi_b * FO + o] + ((deg > 0) ? bias[wi_a * FO + o] : 0.f);

    const int* myadj = (deg > 0) ? (adjp.p[deg - 1] + (size_t)a * deg) : nullptr;
    const uint2* selfrow = reinterpret_cast<const uint2*>(x + (size_t)atom * FINP);

#pragma unroll 1
    for (int st = 0; st < NSF; ++st) {
        const int f0 = st * FS;
        float r[FS];
        load_row<FS / 4>(selfrow + (f0 >> 2), r);
        fma_strip<FS, FO>(r, Wb + f0 * FO, acc);
        if (deg > 0) {
#pragma unroll
            for (int f = 0; f < FS; ++f) r[f] = 0.f;
            for (int k = 0; k < deg; ++k)
                add_row<FS / 4>(reinterpret_cast<const uint2*>(
                    x + (size_t)myadj[k] * FINP) + (f0 >> 2), r);
            fma_strip<FS, FO>(r, Wa + f0 * FO, acc);
        }
    }
    if constexpr (TF > 0) {
        constexpr int f0 = NSF * FS;
        float r[TLD4 * 4];
        load_row<TLD4>(selfrow + (f0 >> 2), r);
        fma_strip<TF, FO>(r, Wb + f0 * FO, acc);
        if (deg > 0) {
#pragma unroll
            for (int f = 0; f < TLD4 * 4; ++f) r[f] = 0.f;
            for (int k = 0; k < deg; ++k)
                add_row<TLD4>(reinterpret_cast<const uint2*>(
                    x + (size_t)myadj[k] * FINP) + (f0 >> 2), r);
            fma_strip<TF, FO>(r, Wa + f0 * FO, acc);
        }
    }

    float outv[FOP];
#pragma unroll
    for (int o = 0; o < FOP; ++o) outv[o] = (o < FO) ? selu_f(acc[o]) : 0.f;
    uint2* yp = reinterpret_cast<uint2*>(y + (size_t)atom * FOP);
#pragma unroll
    for (int v = 0; v < FOP / 4; ++v)
        yp[v] = make_uint2(pack2(outv[4*v], outv[4*v+1]),
                           pack2(outv[4*v+2], outv[4*v+3]));
}

// ---------------------------------------------------------------------------
// inverted-index build: zero -> (count fused in prep) -> scan -> scatter
// ---------------------------------------------------------------------------
__global__ __launch_bounds__(256) void zero_cnt_kernel(int* __restrict__ cnt) {
    const int i = blockIdx.x * NT + threadIdx.x;
    if (i < BATCH_C) cnt[i] = 0;
}
__global__ __launch_bounds__(1024) void scan_kernel(const int* __restrict__ cnt,
                                                    int* __restrict__ base,
                                                    int* __restrict__ cursor) {
    __shared__ int part[1024];
    const int tid = threadIdx.x;
    constexpr int CH = 24;
    const int i0 = tid * CH;
    int sum = 0;
    for (int j = 0; j < CH; ++j) { const int i = i0 + j; if (i < BATCH_C) sum += cnt[i]; }
    part[tid] = sum;
    __syncthreads();
    for (int off = 1; off < 1024; off <<= 1) {
        const int v = (tid >= off) ? part[tid - off] : 0;
        __syncthreads(); part[tid] += v; __syncthreads();
    }
    int run = part[tid] - sum;
    for (int j = 0; j < CH; ++j) {
        const int i = i0 + j;
        if (i < BATCH_C) { base[i] = run; cursor[i] = run; run += cnt[i]; }
    }
    if (tid == 1023) base[BATCH_C] = part[1023];
}
__global__ __launch_bounds__(256) void scatter_kernel(const int* __restrict__ mem,
                                                      int* __restrict__ cursor,
                                                      int* __restrict__ alist) {
    const int i = blockIdx.x * NT + threadIdx.x;
    if (i < N_ATOMS_C) { const int p = atomicAdd(&cursor[mem[i]], 1); alist[p] = i; }
}

// ---------------------------------------------------------------------------
// one wave per molecule: register sum/max over fp16 y4 rows, fused
// tanh -> 72x24 dense -> pairwise softmax
// ---------------------------------------------------------------------------
__global__ __launch_bounds__(256) void reduce_dense_kernel(
    const unsigned short* __restrict__ y4,  // (N, 36) fp16
    const int* __restrict__ base, const int* __restrict__ alist,
    const float* __restrict__ Wd, const float* __restrict__ bd,
    float* __restrict__ out)
{
    __shared__ float sW[72 * 24];
    __shared__ float sb[24];
    __shared__ float molf[4][72];

    const int tid = threadIdx.x;
    for (int i = tid; i < 72 * 24; i += NT) sW[i] = Wd[i];
    if (tid < 24) sb[tid] = bd[tid];
    __syncthreads();

    const int w = tid >> 6, lane = tid & 63;
    const int mol = blockIdx.x * 4 + w;
    const int b0 = base[mol], b1 = base[mol + 1];

    if (lane < 36) {
        float s = 0.f, mx = -INFINITY;
        for (int k = b0; k < b1; ++k) {
            const int atom = alist[k];
            const float v = __half2float(__builtin_bit_cast(__half,
                                y4[(size_t)atom * 36 + lane]));
            s += v; mx = fmaxf(mx, v);
        }
        molf[w][lane] = tanhf(s);
        molf[w][36 + lane] = tanhf(mx);
    }
    __syncthreads();

    if (lane < 24) {
        float l = sb[lane];
#pragma unroll
        for (int f = 0; f < 72; ++f) l += molf[w][f] * sW[f * 24 + lane];
        const float lp = __shfl_xor(l, 1);
        const float m2 = fmaxf(l, lp);
        const float e = expf(l - m2), ep = expf(lp - m2);
        out[(size_t)mol * 24 + lane] = e / (e + ep);
    }
}

// ---------------------------------------------------------------------------
extern "C" void kernel_launch(void* const* d_in, const int* in_sizes, int n_in,
                              void* d_out, int out_size, void* d_ws, size_t ws_size,
                              hipStream_t stream)
{
    const float* x0         = (const float*)d_in[0];
    const int*   membership = (const int*)d_in[2];
    AdjPtrs adj;
    for (int d = 0; d < 10; ++d) adj.p[d] = (const int*)d_in[3 + d];
    const float *W1=(const float*)d_in[13], *b1=(const float*)d_in[14];
    const float *W2=(const float*)d_in[15], *b2=(const float*)d_in[16];
    const float *W3=(const float*)d_in[17], *b3=(const float*)d_in[18];
    const float *W4=(const float*)d_in[19], *b4=(const float*)d_in[20];
    const float *Wd=(const float*)d_in[21], *bd=(const float*)d_in[22];

    // ws layout (bytes):
    //  A [0 .. 81.6M): z planes 4 x (N,16) fp16 = 76.8M (dead after conv1);
    //                  then y2 = A[0..38.4M) (stride 32), y4 = A[38.4..81.6M)
    //  B [szA .. +38.4M): srow (19.2M) + y1 (19.2M at +19.2M);
    //                  after L2 both dead -> y3 = B[0..38.4M)
    //  ints after B
    const size_t szA = 81600000;
    const size_t szB = 38400000;
    const size_t nInts = (size_t)N_ATOMS_C + (BATCH_C + 1) + BATCH_C + BATCH_C;
    if (ws_size < szA + szB + nInts * 4) return;

    char* base0 = (char*)d_ws;
    unsigned short* zbuf = (unsigned short*)base0;
    unsigned short* y2   = (unsigned short*)base0;                      // alias A
    unsigned short* y4   = (unsigned short*)(base0 + 38400000);         // alias A tail
    unsigned short* srow = (unsigned short*)(base0 + szA);
    unsigned short* y1   = (unsigned short*)(base0 + szA + 19200000);
    unsigned short* y3   = (unsigned short*)(base0 + szA);              // alias B after L2
    int* alist  = (int*)(base0 + szA + szB);
    int* base   = alist + N_ATOMS_C;
    int* cursor = base + (BATCH_C + 1);
    int* cnt    = cursor + BATCH_C;

    int nblk = 0;
    for (int d = 0; d < 11; ++d) nblk += (K_COUNTS[d] + NT - 1) / NT;
    const int nb_atoms = (N_ATOMS_C + NT - 1) / NT;

    zero_cnt_kernel<<<(BATCH_C + NT - 1) / NT, NT, 0, stream>>>(cnt);
    prep_kernel<<<nblk, NT, 0, stream>>>(x0, W1, b1, membership, cnt, zbuf, srow);
    scan_kernel<<<1, 1024, 0, stream>>>(cnt, base, cursor);
    scatter_kernel<<<nb_atoms, NT, 0, stream>>>(membership, cursor, alist);

    conv1_kernel<<<nblk, NT, 0, stream>>>(x0, zbuf, srow, W1, adj, y1);
    conv_kernel<15,16,20,32,16><<<nblk, NT, 0, stream>>>(y1, W2, b2, adj, y2);
    conv_kernel<20,32,27,32,32><<<nblk, NT, 0, stream>>>(y2, W3, b3, adj, y3);
    conv_kernel<27,32,36,36,32><<<nblk, NT, 0, stream>>>(y3, W4, b4, adj, y4);

    reduce_dense_kernel<<<BATCH_C / 4, NT, 0, stream>>>(y4, base, alist, Wd, bd, (float*)d_out);
}

// Round 15
// 605.480 us; speedup vs baseline: 1.8915x; 1.8915x over previous
//
#include <hip/hip_runtime.h>
#include <hip/hip_fp16.h>
#include <cstdint>

#define NT 256
#define PT 128                 // prep block threads (2 waves)
#define N_ATOMS_C 600000
#define BATCH_C 24000

constexpr int K_COUNTS[11] = {10000,130000,170000,160000,100000,15000,5000,2500,2500,2500,2500};
constexpr int K_STARTS[11] = {0,10000,140000,310000,470000,570000,585000,590000,592500,595000,597500};
// heavy-degree-first dispatch order
constexpr int DORD[11] = {10,9,8,7,6,5,4,3,2,1,0};

struct AdjPtrs { const int* p[10]; };

typedef _Float16 f16x8 __attribute__((ext_vector_type(8)));
typedef float f32x4 __attribute__((ext_vector_type(4)));

__device__ __forceinline__ float selu_f(float x) {
    const float scale = 1.0507009873554805f;
    const float alpha = 1.6732632423543772f;
    return scale * (x > 0.f ? x : alpha * expm1f(x));
}

__device__ __forceinline__ float2 up2(unsigned u) {
    const __half2 h = __builtin_bit_cast(__half2, u);
    return __half22float2(h);
}
__device__ __forceinline__ unsigned pack2(float a, float b) {
    const __half2 h = __float22half2_rn(make_float2(a, b));
    return __builtin_bit_cast(unsigned, h);
}

template<int NLD4>
__device__ __forceinline__ void load_row(const uint2* __restrict__ p, float* r) {
#pragma unroll
    for (int v = 0; v < NLD4; ++v) {
        const uint2 t = p[v];
        const float2 a = up2(t.x), b = up2(t.y);
        r[4*v] = a.x; r[4*v+1] = a.y; r[4*v+2] = b.x; r[4*v+3] = b.y;
    }
}
template<int NLD4>
__device__ __forceinline__ void add_row(const uint2* __restrict__ p, float* r) {
#pragma unroll
    for (int v = 0; v < NLD4; ++v) {
        const uint2 t = p[v];
        const float2 a = up2(t.x), b = up2(t.y);
        r[4*v] += a.x; r[4*v+1] += a.y; r[4*v+2] += b.x; r[4*v+3] += b.y;
    }
}
template<int NF, int FO>
__device__ __forceinline__ void fma_strip(const float* r, const float* __restrict__ w,
                                          float* acc) {
#pragma unroll
    for (int f = 0; f < NF; ++f)
#pragma unroll
        for (int o = 0; o < FO; ++o)
            acc[o] = fmaf(r[f], w[f * FO + o], acc[o]);
}

// block -> (degree, segment start, count, tile index within segment)
template<int TB>
__device__ __forceinline__ void blk2degT(int blk, int& deg, int& s, int& cnt, int& tile) {
    deg = 0; s = 0; cnt = 0; tile = 0;
#pragma unroll
    for (int di = 0; di < 11; ++di) {
        const int d = DORD[di];
        const int nb = (K_COUNTS[d] + TB - 1) / TB;
        if (blk < nb) { deg = d; s = K_STARTS[d]; cnt = K_COUNTS[d]; tile = blk; return; }
        blk -= nb;
    }
}

// ---------------------------------------------------------------------------
// prep (MFMA): per block of 128 atoms, C[128][80] = A[128][76pad96] @ B[76][80]
// where B = 5 weight slices {W0,W2,W4,W6,Wb(deg)} as 16-wide column groups.
// A and B^T staged in LDS fp16 at stride 104 (208B -> 2-way bank alias, free).
// Each of 2 waves: 64 atoms x 80 outs = 20 C-tiles x 3 K-steps = 60
// v_mfma_f32_16x16x32_f16. r12-r14 showed VALU/operand-supply-bound scalar
// paths plateau at 244-755us; MFMA-pipe cost for this GEMM is ~5us chip-wide.
// Fragment layouts: A row=lane&15,k=(lane>>4)*8+j; B col=lane&15 (from B^T);
// C/D col=lane&15,row=(lane>>4)*4+reg (guide-verified, dtype-independent).
// Membership histogram fused.
// ---------------------------------------------------------------------------
__global__ __launch_bounds__(128) void prep_kernel(
    const float* __restrict__ x0,    // (N, 75) f32
    const float* __restrict__ W,     // (21, 75, 15) f32
    const float* __restrict__ bias,  // (21, 15)
    const int* __restrict__ mem,
    int* __restrict__ cnt,
    unsigned short* __restrict__ z,  // 4 planes of (N, 16) fp16
    unsigned short* __restrict__ srow) // (N, 16) fp16
{
    __shared__ _Float16 sx[PT * 104];   // A: 128 rows x 104 (26.6 KB)
    __shared__ _Float16 sb[80 * 104];   // B^T: 80 cols x 104 k (16.6 KB)

    int deg, s, c, tile;
    blk2degT<PT>(blockIdx.x, deg, s, c, tile);
    const int a0 = tile * PT;
    const int na = min(PT, c - a0);
    const int tid = threadIdx.x;
    const int wi_b = deg ? (2 * deg - 1) : 20;

    // stage A: na x 75 f32 -> fp16 LDS (coalesced)
    const float* src = x0 + (size_t)(s + a0) * 75;
    for (int i = tid; i < na * 75; i += PT) {
        const int j = i / 75, f = i - j * 75;
        sx[j * 104 + f] = (_Float16)src[i];
    }
    // zero A pad cols 75..103 (all 128 rows: stale LDS could be Inf/NaN)
    for (int i = tid; i < PT * 29; i += PT) {
        const int j = i / 29, f = 75 + (i - j * 29);
        sx[j * 104 + f] = (_Float16)0.f;
    }
    // stage B^T: col = 16*p + o, val = W[wi_p][k][o]; zero pads
    for (int i = tid; i < 80 * 104; i += PT) {
        const int col = i / 104, k = i - col * 104;
        const int p = col >> 4, o = col & 15;
        const int wi = (p < 4) ? 2 * p : wi_b;
        const float v = (k < 75 && o < 15) ? W[wi * 1125 + k * 15 + o] : 0.f;
        sb[col * 104 + k] = (_Float16)v;
    }
    __syncthreads();

    if (tid < na) atomicAdd(&cnt[mem[s + a0 + tid]], 1);

    const int lane = tid & 63, w = tid >> 6;
    const int lrow = lane & 15;          // A row in tile / B^T row (=col of B)
    const int kgrp = (lane >> 4) * 8;    // k offset within K-step
    const int row0 = (lane >> 4) * 4;    // C row base
    const int colo = lane & 15;          // C col

    float badd = 0.f;
    if (colo < 15)
        badd = bias[wi_b * 15 + colo] + (deg ? bias[2 * (deg - 1) * 15 + colo] : 0.f);

    // hoist A fragments: 4 M-tiles x 3 K-steps
    f16x8 af[4][3];
#pragma unroll
    for (int mt = 0; mt < 4; ++mt)
#pragma unroll
        for (int ks = 0; ks < 3; ++ks)
            af[mt][ks] = *(const f16x8*)&sx[(w * 64 + mt * 16 + lrow) * 104 + ks * 32 + kgrp];

#pragma unroll
    for (int nt = 0; nt < 5; ++nt) {     // N-tile == projection p
        f16x8 bf[3];
#pragma unroll
        for (int ks = 0; ks < 3; ++ks)
            bf[ks] = *(const f16x8*)&sb[(nt * 16 + lrow) * 104 + ks * 32 + kgrp];
#pragma unroll
        for (int mt = 0; mt < 4; ++mt) {
            f32x4 acc = {0.f, 0.f, 0.f, 0.f};
#pragma unroll
            for (int ks = 0; ks < 3; ++ks)
                acc = __builtin_amdgcn_mfma_f32_16x16x32_f16(af[mt][ks], bf[ks], acc, 0, 0, 0);
#pragma unroll
            for (int reg = 0; reg < 4; ++reg) {
                const int ar = w * 64 + mt * 16 + row0 + reg;
                if (ar < na) {
                    const size_t atom = (size_t)(s + a0 + ar);
                    if (nt < 4) {
                        z[(size_t)nt * ((size_t)N_ATOMS_C * 16) + atom * 16 + colo] =
                            __builtin_bit_cast(unsigned short, (_Float16)acc[reg]);
                    } else {
                        const float v = (colo < 15) ? acc[reg] + badd : 0.f;
                        srow[atom * 16 + colo] =
                            __builtin_bit_cast(unsigned short, (_Float16)v);
                    }
                }
            }
        }
    }
}

// ---------------------------------------------------------------------------
// conv1: deg<=4 -> s + sum of gathered 32-B rows (2 x uint4) from z plane.
//        deg>=5 -> s + full x0-row gathers vs Wa (rare: 190K rows).
// ---------------------------------------------------------------------------
__global__ __launch_bounds__(256) void conv1_kernel(
    const float* __restrict__ x0,
    const unsigned short* __restrict__ z,     // 4 planes of (N,16)
    const unsigned short* __restrict__ srow,
    const float* __restrict__ W,
    AdjPtrs adjp,
    unsigned short* __restrict__ y1)  // (N, 16) fp16
{
    int deg, s, c, tile;
    blk2degT<NT>(blockIdx.x, deg, s, c, tile);
    const int a = tile * NT + threadIdx.x;
    if (a >= c) return;
    const int atom = s + a;

    float acc[15];
    {
        const uint2* sp = reinterpret_cast<const uint2*>(srow + (size_t)atom * 16);
        float r[16];
        load_row<4>(sp, r);
#pragma unroll
        for (int o = 0; o < 15; ++o) acc[o] = r[o];
    }

    if (deg >= 1 && deg <= 4) {
        const unsigned short* zd = z + (size_t)(deg - 1) * ((size_t)N_ATOMS_C * 16);
        const int* ad = adjp.p[deg - 1] + (size_t)a * deg;
        int nb[4];
#pragma unroll
        for (int k = 0; k < 4; ++k) nb[k] = ad[k < deg ? k : 0];
        uint4 t[4][2];
#pragma unroll
        for (int k = 0; k < 4; ++k) {
            const uint4* p = reinterpret_cast<const uint4*>(zd + (size_t)nb[k] * 16);
            t[k][0] = p[0]; t[k][1] = p[1];
        }
#pragma unroll
        for (int k = 0; k < 4; ++k) {
            if (k < deg) {
                const unsigned w[8] = {t[k][0].x, t[k][0].y, t[k][0].z, t[k][0].w,
                                       t[k][1].x, t[k][1].y, t[k][1].z, t[k][1].w};
#pragma unroll
                for (int v = 0; v < 8; ++v) {
                    const float2 lo = up2(w[v]);
                    if (2 * v < 15)     acc[2 * v]     += lo.x;
                    if (2 * v + 1 < 15) acc[2 * v + 1] += lo.y;
                }
            }
        }
    } else if (deg >= 5) {
        const float* Wa = W + 2 * (deg - 1) * 1125;
        const int* ad = adjp.p[deg - 1] + (size_t)a * deg;
#pragma unroll 1
        for (int st = 0; st < 3; ++st) {
            float r[25];
#pragma unroll
            for (int j = 0; j < 25; ++j) r[j] = 0.f;
            for (int k = 0; k < deg; ++k) {
                const float* xr = x0 + (size_t)ad[k] * 75 + st * 25;
#pragma unroll
                for (int j = 0; j < 25; ++j) r[j] += xr[j];
            }
            fma_strip<25, 15>(r, Wa + st * 25 * 15, acc);
        }
    }

    uint2* yp = reinterpret_cast<uint2*>(y1 + (size_t)atom * 16);
    float o_[16];
#pragma unroll
    for (int o = 0; o < 16; ++o) o_[o] = (o < 15) ? selu_f(acc[o]) : 0.f;
    yp[0] = make_uint2(pack2(o_[0],o_[1]),  pack2(o_[2],o_[3]));
    yp[1] = make_uint2(pack2(o_[4],o_[5]),  pack2(o_[6],o_[7]));
    yp[2] = make_uint2(pack2(o_[8],o_[9]),  pack2(o_[10],o_[11]));
    yp[3] = make_uint2(pack2(o_[12],o_[13]),pack2(o_[14],o_[15]));
}

// ---------------------------------------------------------------------------
// Generic conv (layers 2-4): thread = atom, fp16 in/out, f32 accum.
// ---------------------------------------------------------------------------
template<int FIN, int FINP, int FO, int FOP, int FS>
__global__ __launch_bounds__(256) void conv_kernel(
    const unsigned short* __restrict__ x,  // (N, FINP) fp16
    const float* __restrict__ W,           // (21, FIN, FO)
    const float* __restrict__ bias,        // (21, FO)
    AdjPtrs adjp,
    unsigned short* __restrict__ y)        // (N, FOP) fp16
{
    static_assert(FS % 4 == 0 && FINP % 4 == 0 && FOP % 4 == 0, "");
    constexpr int NSF = FIN / FS;
    constexpr int TF  = FIN - NSF * FS;
    constexpr int TLD4 = (TF + 3) / 4;
    static_assert(NSF * FS + TLD4 * 4 <= FINP, "tail reads past row");

    int deg, s, c, tile;
    blk2degT<NT>(blockIdx.x, deg, s, c, tile);
    const int a = tile * NT + threadIdx.x;
    if (a >= c) return;
    const int atom = s + a;

    const int wi_a = (deg == 0) ? 20 : 2 * (deg - 1);
    const int wi_b = (deg == 0) ? 20 : 2 * deg - 1;
    const float* Wa = W + wi_a * FIN * FO;
    const float* Wb = W + wi_b * FIN * FO;

    float acc[FO];
#pragma unroll
    for (int o = 0; o < FO; ++o)
        acc[o] = bias[wi_b * FO + o] + ((deg > 0) ? bias[wi_a * FO + o] : 0.f);

    const int* myadj = (deg > 0) ? (adjp.p[deg - 1] + (size_t)a * deg) : nullptr;
    const uint2* selfrow = reinterpret_cast<const uint2*>(x + (size_t)atom * FINP);

#pragma unroll 1
    for (int st = 0; st < NSF; ++st) {
        const int f0 = st * FS;
        float r[FS];
        load_row<FS / 4>(selfrow + (f0 >> 2), r);
        fma_strip<FS, FO>(r, Wb + f0 * FO, acc);
        if (deg > 0) {
#pragma unroll
            for (int f = 0; f < FS; ++f) r[f] = 0.f;
            for (int k = 0; k < deg; ++k)
                add_row<FS / 4>(reinterpret_cast<const uint2*>(
                    x + (size_t)myadj[k] * FINP) + (f0 >> 2), r);
            fma_strip<FS, FO>(r, Wa + f0 * FO, acc);
        }
    }
    if constexpr (TF > 0) {
        constexpr int f0 = NSF * FS;
        float r[TLD4 * 4];
        load_row<TLD4>(selfrow + (f0 >> 2), r);
        fma_strip<TF, FO>(r, Wb + f0 * FO, acc);
        if (deg > 0) {
#pragma unroll
            for (int f = 0; f < TLD4 * 4; ++f) r[f] = 0.f;
            for (int k = 0; k < deg; ++k)
                add_row<TLD4>(reinterpret_cast<const uint2*>(
                    x + (size_t)myadj[k] * FINP) + (f0 >> 2), r);
            fma_strip<TF, FO>(r, Wa + f0 * FO, acc);
        }
    }

    float outv[FOP];
#pragma unroll
    for (int o = 0; o < FOP; ++o) outv[o] = (o < FO) ? selu_f(acc[o]) : 0.f;
    uint2* yp = reinterpret_cast<uint2*>(y + (size_t)atom * FOP);
#pragma unroll
    for (int v = 0; v < FOP / 4; ++v)
        yp[v] = make_uint2(pack2(outv[4*v], outv[4*v+1]),
                           pack2(outv[4*v+2], outv[4*v+3]));
}

// ---------------------------------------------------------------------------
// inverted-index build: zero -> (count fused in prep) -> scan -> scatter
// ---------------------------------------------------------------------------
__global__ __launch_bounds__(256) void zero_cnt_kernel(int* __restrict__ cnt) {
    const int i = blockIdx.x * NT + threadIdx.x;
    if (i < BATCH_C) cnt[i] = 0;
}
__global__ __launch_bounds__(1024) void scan_kernel(const int* __restrict__ cnt,
                                                    int* __restrict__ base,
                                                    int* __restrict__ cursor) {
    __shared__ int part[1024];
    const int tid = threadIdx.x;
    constexpr int CH = 24;
    const int i0 = tid * CH;
    int sum = 0;
    for (int j = 0; j < CH; ++j) { const int i = i0 + j; if (i < BATCH_C) sum += cnt[i]; }
    part[tid] = sum;
    __syncthreads();
    for (int off = 1; off < 1024; off <<= 1) {
        const int v = (tid >= off) ? part[tid - off] : 0;
        __syncthreads(); part[tid] += v; __syncthreads();
    }
    int run = part[tid] - sum;
    for (int j = 0; j < CH; ++j) {
        const int i = i0 + j;
        if (i < BATCH_C) { base[i] = run; cursor[i] = run; run += cnt[i]; }
    }
    if (tid == 1023) base[BATCH_C] = part[1023];
}
__global__ __launch_bounds__(256) void scatter_kernel(const int* __restrict__ mem,
                                                      int* __restrict__ cursor,
                                                      int* __restrict__ alist) {
    const int i = blockIdx.x * NT + threadIdx.x;
    if (i < N_ATOMS_C) { const int p = atomicAdd(&cursor[mem[i]], 1); alist[p] = i; }
}

// ---------------------------------------------------------------------------
// one wave per molecule: register sum/max over fp16 y4 rows, fused
// tanh -> 72x24 dense -> pairwise softmax
// ---------------------------------------------------------------------------
__global__ __launch_bounds__(256) void reduce_dense_kernel(
    const unsigned short* __restrict__ y4,  // (N, 36) fp16
    const int* __restrict__ base, const int* __restrict__ alist,
    const float* __restrict__ Wd, const float* __restrict__ bd,
    float* __restrict__ out)
{
    __shared__ float sW[72 * 24];
    __shared__ float sb[24];
    __shared__ float molf[4][72];

    const int tid = threadIdx.x;
    for (int i = tid; i < 72 * 24; i += NT) sW[i] = Wd[i];
    if (tid < 24) sb[tid] = bd[tid];
    __syncthreads();

    const int w = tid >> 6, lane = tid & 63;
    const int mol = blockIdx.x * 4 + w;
    const int b0 = base[mol], b1 = base[mol + 1];

    if (lane < 36) {
        float s = 0.f, mx = -INFINITY;
        for (int k = b0; k < b1; ++k) {
            const int atom = alist[k];
            const float v = __half2float(__builtin_bit_cast(__half,
                                y4[(size_t)atom * 36 + lane]));
            s += v; mx = fmaxf(mx, v);
        }
        molf[w][lane] = tanhf(s);
        molf[w][36 + lane] = tanhf(mx);
    }
    __syncthreads();

    if (lane < 24) {
        float l = sb[lane];
#pragma unroll
        for (int f = 0; f < 72; ++f) l += molf[w][f] * sW[f * 24 + lane];
        const float lp = __shfl_xor(l, 1);
        const float m2 = fmaxf(l, lp);
        const float e = expf(l - m2), ep = expf(lp - m2);
        out[(size_t)mol * 24 + lane] = e / (e + ep);
    }
}

// ---------------------------------------------------------------------------
extern "C" void kernel_launch(void* const* d_in, const int* in_sizes, int n_in,
                              void* d_out, int out_size, void* d_ws, size_t ws_size,
                              hipStream_t stream)
{
    const float* x0         = (const float*)d_in[0];
    const int*   membership = (const int*)d_in[2];
    AdjPtrs adj;
    for (int d = 0; d < 10; ++d) adj.p[d] = (const int*)d_in[3 + d];
    const float *W1=(const float*)d_in[13], *b1=(const float*)d_in[14];
    const float *W2=(const float*)d_in[15], *b2=(const float*)d_in[16];
    const float *W3=(const float*)d_in[17], *b3=(const float*)d_in[18];
    const float *W4=(const float*)d_in[19], *b4=(const float*)d_in[20];
    const float *Wd=(const float*)d_in[21], *bd=(const float*)d_in[22];

    // ws layout (bytes):
    //  A [0 .. 81.6M): z planes 4 x (N,16) fp16 = 76.8M (dead after conv1);
    //                  then y2 = A[0..38.4M) (stride 32), y4 = A[38.4..81.6M)
    //  B [szA .. +38.4M): srow (19.2M) + y1 (19.2M at +19.2M);
    //                  after L2 both dead -> y3 = B[0..38.4M)
    //  ints after B
    const size_t szA = 81600000;
    const size_t szB = 38400000;
    const size_t nInts = (size_t)N_ATOMS_C + (BATCH_C + 1) + BATCH_C + BATCH_C;
    if (ws_size < szA + szB + nInts * 4) return;

    char* base0 = (char*)d_ws;
    unsigned short* zbuf = (unsigned short*)base0;
    unsigned short* y2   = (unsigned short*)base0;                      // alias A
    unsigned short* y4   = (unsigned short*)(base0 + 38400000);         // alias A tail
    unsigned short* srow = (unsigned short*)(base0 + szA);
    unsigned short* y1   = (unsigned short*)(base0 + szA + 19200000);
    unsigned short* y3   = (unsigned short*)(base0 + szA);              // alias B after L2
    int* alist  = (int*)(base0 + szA + szB);
    int* base   = alist + N_ATOMS_C;
    int* cursor = base + (BATCH_C + 1);
    int* cnt    = cursor + BATCH_C;

    int nblk = 0, nblkp = 0;
    for (int d = 0; d < 11; ++d) {
        nblk  += (K_COUNTS[d] + NT - 1) / NT;
        nblkp += (K_COUNTS[d] + PT - 1) / PT;
    }
    const int nb_atoms = (N_ATOMS_C + NT - 1) / NT;

    zero_cnt_kernel<<<(BATCH_C + NT - 1) / NT, NT, 0, stream>>>(cnt);
    prep_kernel<<<nblkp, PT, 0, stream>>>(x0, W1, b1, membership, cnt, zbuf, srow);
    scan_kernel<<<1, 1024, 0, stream>>>(cnt, base, cursor);
    scatter_kernel<<<nb_atoms, NT, 0, stream>>>(membership, cursor, alist);

    conv1_kernel<<<nblk, NT, 0, stream>>>(x0, zbuf, srow, W1, adj, y1);
    conv_kernel<15,16,20,32,16><<<nblk, NT, 0, stream>>>(y1, W2, b2, adj, y2);
    conv_kernel<20,32,27,32,32><<<nblk, NT, 0, stream>>>(y2, W3, b3, adj, y3);
    conv_kernel<27,32,36,36,32><<<nblk, NT, 0, stream>>>(y3, W4, b4, adj, y4);

    reduce_dense_kernel<<<BATCH_C / 4, NT, 0, stream>>>(y4, base, alist, Wd, bd, (float*)d_out);
}